// Round 7
// baseline (1113.360 us; speedup 1.0000x reference)
//
#include <hip/hip_runtime.h>

#define VIEWS 6
#define NPTS 20000
#define DIM 512
#define M_TOTAL (VIEWS * NPTS)

typedef __bf16 bf16_t;
typedef __attribute__((ext_vector_type(8))) __bf16 bf16x8;
typedef __attribute__((ext_vector_type(4))) float f32x4;

// ---- workspace byte offsets ----
#define OFF_XB 0L                      // X bf16  [6][20000][512]
#define OFF_QB 122880000L              // Q0 bf16
#define OFF_KB 245760000L              // K0 bf16
#define OFF_VB 368640000L              // V0 bf16
#define OFF_WB 491520000L              // W bf16  [3][512][512]
#define OFF_F32 493092864L             // fp32 stats region
// ---- float indices inside fp32 region ----
#define S_SUM 0                        // [3][6][512] per-channel sums
#define S_SSQ 9216                     // [3][6][512] per-channel sum-squares
#define S_PPRE 18432                   // [36] weighted gram accumulator
#define S_COEFA 18468                  // [3][512] BN scale a
#define S_COEFC 20004                  // [3][512] BN shift c
#define S_INVN 21540                   // [3][6] inverse Fro norms
#define S_P 21558                      // [36] final mixing matrix
#define S_END 21594

__device__ __forceinline__ void gload_lds16(const void* gsrc, void* lds) {
    __builtin_amdgcn_global_load_lds(
        (const __attribute__((address_space(1))) unsigned int*)gsrc,
        (__attribute__((address_space(3))) unsigned int*)lds,
        16, 0, 0);
}

// ---------------------------------------------------------------------------
// K0: fp32 -> bf16 convert (8 elems/thread/iter)
// ---------------------------------------------------------------------------
__global__ __launch_bounds__(256) void convert_bf16(
    const float* __restrict__ src, bf16_t* __restrict__ dst, long n8)
{
    long i = (long)blockIdx.x * blockDim.x + threadIdx.x;
    const long stride = (long)gridDim.x * blockDim.x;
    for (; i < n8; i += stride) {
        const float4* s = (const float4*)(src + i * 8);
        float4 x = s[0], y = s[1];
        bf16x8 o;
        o[0] = (bf16_t)x.x; o[1] = (bf16_t)x.y; o[2] = (bf16_t)x.z; o[3] = (bf16_t)x.w;
        o[4] = (bf16_t)y.x; o[5] = (bf16_t)y.y; o[6] = (bf16_t)y.z; o[7] = (bf16_t)y.w;
        *(bf16x8*)(dst + i * 8) = o;
    }
}

// ---------------------------------------------------------------------------
// K1: bf16 MFMA GEMM  [Q0|K0|V0] = X @ W^T  (+bias, fp32 stats, bf16 store)
// One block: 64 rows x 64 cols x ALL THREE tensors (A staged once, 3x W).
// LDS XOR-swizzle kc^=(row&7) on both stage-source and ds_read (rule 21).
// 1D grid 15024 = 313 n-tiles x 8 c-tiles x 6 views, XCD-chunk swizzled so
// the 8 c-tile blocks sharing an A tile land consecutively on one XCD.
// ---------------------------------------------------------------------------
__global__ __launch_bounds__(256, 4) void gemm_qkv_mfma(
    const bf16_t* __restrict__ XB, const bf16_t* __restrict__ WB,
    const float* __restrict__ b0, const float* __restrict__ b1,
    const float* __restrict__ b2,
    float* __restrict__ statS, float* __restrict__ statQ,
    bf16_t* __restrict__ QB, bf16_t* __restrict__ KB, bf16_t* __restrict__ VB)
{
    // bijective XCD swizzle: nwg=15024=8*1878; logical L-consecutive -> same XCD
    const int orig = blockIdx.x;
    const int L    = (orig & 7) * 1878 + (orig >> 3);
    const int n0i  = L / 48;
    const int rem  = L - n0i * 48;
    const int v    = rem >> 3;            // view
    const int c0   = (rem & 7) << 6;      // channel tile base (64 wide)
    const int n0   = n0i * 64;
    const int nvalid = min(64, NPTS - n0);

    const int tid  = threadIdx.x;
    const int wid  = tid >> 6;
    const int lane = tid & 63;
    const int lr   = lane & 15;
    const int lk   = lane >> 4;
    const int wm   = wid >> 1;            // wave row 0..1 (32 rows each)
    const int wn   = wid & 1;             // wave col 0..1 (32 cols each)

    // LDS: As[64][64] ushort (8KB) + Bs[3][64][64] (24KB) = 32KB
    __shared__ char smem[32768];

    const bf16_t* Ag = XB + ((long)v * NPTS + n0) * DIM;

    f32x4 acc[3][2][2];
    const f32x4 zero4 = {0.f, 0.f, 0.f, 0.f};
#pragma unroll
    for (int t = 0; t < 3; ++t)
#pragma unroll
        for (int i = 0; i < 2; ++i)
#pragma unroll
            for (int j = 0; j < 2; ++j) acc[t][i][j] = zero4;

    for (int k0 = 0; k0 < DIM; k0 += 64) {
        __syncthreads();
        // stage 2048 chunks of 16B: 512 A + 3*512 B. 8 iters x 256 lanes.
        // source kc pre-swizzled (kc ^ row&7); LDS dest linear.
#pragma unroll
        for (int i = 0; i < 8; ++i) {
            const int base = i * 256 + wid * 64;     // wave-uniform
            const int g    = base + lane;
            const bf16_t* src;
            if (g < 512) {                           // A chunk (uniform per wave)
                const int row = g >> 3;
                const int kcs = (g & 7) ^ (row & 7);
                const int rowc = (row < nvalid) ? row : (nvalid - 1);
                src = Ag + (long)rowc * DIM + k0 + kcs * 8;
            } else {                                 // B chunk
                const int h   = g - 512;
                const int t   = h >> 9;
                const int idx = h & 511;
                const int row = idx >> 3;
                const int kcs = (idx & 7) ^ (row & 7);
                src = WB + ((long)t << 18) + (long)(c0 + row) * DIM + k0 + kcs * 8;
            }
            gload_lds16(src, smem + (long)base * 16);
        }
        __syncthreads();
#pragma unroll
        for (int ks = 0; ks < 2; ++ks) {
            const int kc = ks * 4 + lk;
            bf16x8 af[2];
#pragma unroll
            for (int fm = 0; fm < 2; ++fm) {
                const int rowA = wm * 32 + fm * 16 + lr;
                af[fm] = *(const bf16x8*)(smem + rowA * 128 + ((kc ^ (rowA & 7)) << 4));
            }
#pragma unroll
            for (int t = 0; t < 3; ++t) {
#pragma unroll
                for (int fn = 0; fn < 2; ++fn) {
                    const int rowB = wn * 32 + fn * 16 + lr;
                    bf16x8 bf = *(const bf16x8*)(smem + 8192 + t * 8192 +
                                                 rowB * 128 + ((kc ^ (rowB & 7)) << 4));
#pragma unroll
                    for (int fm = 0; fm < 2; ++fm)
                        acc[t][fm][fn] = __builtin_amdgcn_mfma_f32_16x16x32_bf16(
                            af[fm], bf, acc[t][fm][fn], 0, 0, 0);
                }
            }
        }
    }

    // epilogue: per tensor: bias, bf16 store, per-channel stats
    __syncthreads();
    float* redS = (float*)smem;          // alias dead As region
    float* redQ = redS + 64;
    for (int t = 0; t < 3; ++t) {
        if (tid < 128) redS[tid] = 0.f;  // zeroes redS[64]+redQ[64]
        __syncthreads();
        bf16_t* Obuf = (t == 0) ? QB : (t == 1) ? KB : VB;
        const float* bias = (t == 0) ? b0 : (t == 1) ? b1 : b2;
#pragma unroll
        for (int fn = 0; fn < 2; ++fn) {
            const int cl  = wn * 32 + fn * 16 + lr;
            const int col = c0 + cl;
            const float bv_ = bias[col];
            float cs = 0.f, cq = 0.f;
#pragma unroll
            for (int fm = 0; fm < 2; ++fm) {
#pragma unroll
                for (int r = 0; r < 4; ++r) {
                    const int row = wm * 32 + fm * 16 + lk * 4 + r;
                    if (row < nvalid) {
                        float val = acc[t][fm][fn][r] + bv_;
                        cs += val;
                        cq += val * val;
                        Obuf[((long)v * NPTS + n0 + row) * DIM + col] = (bf16_t)val;
                    }
                }
            }
            atomicAdd(&redS[cl], cs);
            atomicAdd(&redQ[cl], cq);
        }
        __syncthreads();
        if (tid < 64) {
            atomicAdd(&statS[(((long)t * 6 + v) << 9) + c0 + tid], redS[tid]);
            atomicAdd(&statQ[(((long)t * 6 + v) << 9) + c0 + tid], redQ[tid]);
        }
        __syncthreads();
    }
}

// ---------------------------------------------------------------------------
// K2: BN affine coefficients + per-view inverse Frobenius norms
// ---------------------------------------------------------------------------
__global__ __launch_bounds__(512) void finalize_stats(
    const float* __restrict__ gq, const float* __restrict__ beq,
    const float* __restrict__ gk, const float* __restrict__ bek,
    const float* __restrict__ gv, const float* __restrict__ bev,
    float* __restrict__ ws2)
{
    const int t = blockIdx.x;
    const int c = threadIdx.x;
    const float* g  = (t == 0) ? gq : (t == 1) ? gk : gv;
    const float* be = (t == 0) ? beq : (t == 1) ? bek : bev;
    const float* sumbuf = ws2 + S_SUM + (long)t * 6 * 512;
    const float* ssqbuf = ws2 + S_SSQ + (long)t * 6 * 512;

    float s[6], q[6];
    float tot = 0.f, totq = 0.f;
#pragma unroll
    for (int v = 0; v < 6; ++v) {
        s[v] = sumbuf[v * 512 + c];
        q[v] = ssqbuf[v * 512 + c];
        tot += s[v]; totq += q[v];
    }
    const float invM = 1.0f / (float)M_TOTAL;
    float mean = tot * invM;
    float var  = totq * invM - mean * mean;
    float a    = g[c] * rsqrtf(var + 1e-5f);
    float cc   = be[c] - a * mean;
    ws2[S_COEFA + t * 512 + c] = a;
    ws2[S_COEFC + t * 512 + c] = cc;

    __shared__ float red[512];
    for (int v = 0; v < 6; ++v) {
        red[c] = a * a * q[v] + 2.f * a * cc * s[v] + (float)NPTS * cc * cc;
        __syncthreads();
        for (int off = 256; off > 0; off >>= 1) {
            if (c < off) red[c] += red[c + off];
            __syncthreads();
        }
        if (c == 0) ws2[S_INVN + t * 6 + v] = 1.f / (sqrtf(red[0]) + 1e-8f);
        __syncthreads();
    }
}

// ---------------------------------------------------------------------------
// K3: weighted gram  PPRE[i][j] += sum_{n,c} (aq_c*ak_c) Q0[i,n,c] K0[j,n,c]
// ---------------------------------------------------------------------------
__global__ __launch_bounds__(256) void qk_dot(
    const bf16_t* __restrict__ QB, const bf16_t* __restrict__ KB,
    float* __restrict__ ws2)
{
    float acc[36];
#pragma unroll
    for (int c = 0; c < 36; ++c) acc[c] = 0.f;

    const float* cA = ws2 + S_COEFA;
    const long total = (long)NPTS * 64;
    for (long it = (long)blockIdx.x * 256 + threadIdx.x; it < total;
         it += (long)gridDim.x * 256) {
        const int n  = (int)(it >> 6);
        const int d8 = (int)(it & 63);

        float w8[8];
#pragma unroll
        for (int e = 0; e < 8; ++e)
            w8[e] = cA[d8 * 8 + e] * cA[512 + d8 * 8 + e];

        float qw[6][8];
#pragma unroll
        for (int i = 0; i < 6; ++i) {
            bf16x8 qv = *(const bf16x8*)(QB + ((long)i * NPTS + n) * DIM + d8 * 8);
#pragma unroll
            for (int e = 0; e < 8; ++e) qw[i][e] = (float)qv[e] * w8[e];
        }
#pragma unroll
        for (int j = 0; j < 6; ++j) {
            bf16x8 kv = *(const bf16x8*)(KB + ((long)j * NPTS + n) * DIM + d8 * 8);
            float kf[8];
#pragma unroll
            for (int e = 0; e < 8; ++e) kf[e] = (float)kv[e];
#pragma unroll
            for (int i = 0; i < 6; ++i) {
                float d = 0.f;
#pragma unroll
                for (int e = 0; e < 8; ++e) d = fmaf(qw[i][e], kf[e], d);
                acc[i * 6 + j] += d;
            }
        }
    }

    __shared__ float part[36];
    if (threadIdx.x < 36) part[threadIdx.x] = 0.f;
    __syncthreads();
    const int lane = threadIdx.x & 63;
#pragma unroll
    for (int c = 0; c < 36; ++c) {
        float x = acc[c];
#pragma unroll
        for (int m = 1; m < 64; m <<= 1) x += __shfl_xor(x, m);
        if (lane == 0) atomicAdd(&part[c], x);
    }
    __syncthreads();
    if (threadIdx.x < 36) atomicAdd(&ws2[S_PPRE + threadIdx.x], part[threadIdx.x]);
}

// ---------------------------------------------------------------------------
// K4: cross terms + sigmoid + softmax mix + 10-step projection
// ---------------------------------------------------------------------------
__global__ __launch_bounds__(512) void project_kernel(float* __restrict__ ws2)
{
    const int c = threadIdx.x;   // 0..511
    __shared__ float red[512];
    const float aq = ws2[S_COEFA + c],       cq = ws2[S_COEFC + c];
    const float ak = ws2[S_COEFA + 512 + c], ck = ws2[S_COEFC + 512 + c];

    float vals[13];
#pragma unroll
    for (int i = 0; i < 6; ++i) vals[i]     = aq * ck * ws2[S_SUM + i * 512 + c];
#pragma unroll
    for (int j = 0; j < 6; ++j) vals[6 + j] = cq * ak * ws2[S_SUM + (6 + j) * 512 + c];
    vals[12] = cq * ck;

    float out13[13];
#pragma unroll
    for (int r = 0; r < 13; ++r) {
        red[c] = vals[r];
        __syncthreads();
        for (int off = 256; off > 0; off >>= 1) {
            if (c < off) red[c] += red[c + off];
            __syncthreads();
        }
        out13[r] = red[0];
        __syncthreads();
    }

    if (c != 0) return;

    const float* invn = ws2 + S_INVN;
    float p[6][6];
    for (int i = 0; i < 6; ++i)
        for (int j = 0; j < 6; ++j) {
            float raw = ws2[S_PPRE + i * 6 + j] + out13[i] + out13[6 + j] +
                        (float)NPTS * out13[12];
            float z = raw * invn[i] * invn[6 + j];
            p[i][j] = 1.f / (1.f + expf(-z));
        }
    float s0[6][6], s1[6][6];
    for (int j = 0; j < 6; ++j) {
        float m = -1e30f;
        for (int i = 0; i < 6; ++i) m = fmaxf(m, p[i][j]);
        float sum = 0.f;
        for (int i = 0; i < 6; ++i) { s0[i][j] = expf(p[i][j] - m); sum += s0[i][j]; }
        for (int i = 0; i < 6; ++i) s0[i][j] /= sum;
    }
    for (int i = 0; i < 6; ++i) {
        float m = -1e30f;
        for (int j = 0; j < 6; ++j) m = fmaxf(m, p[i][j]);
        float sum = 0.f;
        for (int j = 0; j < 6; ++j) { s1[i][j] = expf(p[i][j] - m); sum += s1[i][j]; }
        for (int j = 0; j < 6; ++j) s1[i][j] /= sum;
    }
    for (int i = 0; i < 6; ++i)
        for (int j = 0; j < 6; ++j) p[i][j] = 0.5f * (s0[i][j] + s1[i][j]);

    for (int itr = 0; itr < 10; ++itr) {
        float p1[6][6];
        for (int i = 0; i < 6; ++i)
            for (int j = 0; j < 6; ++j) p1[i][j] = fmaxf(p[i][j], 0.f);
        for (int i = 0; i < 6; ++i) {
            float rs = 0.f;
            for (int j = 0; j < 6; ++j) rs += p1[i][j];
            float adj = (rs - 1.f) * (1.f / 6.f);
            for (int j = 0; j < 6; ++j) p1[i][j] -= adj;
        }
        for (int j = 0; j < 6; ++j) {
            float cs = 0.f;
            for (int i = 0; i < 6; ++i) cs += p1[i][j];
            float adj = (cs - 1.f) * (1.f / 6.f);
            for (int i = 0; i < 6; ++i) p1[i][j] -= adj;
        }
        for (int i = 0; i < 6; ++i)
            for (int j = 0; j < 6; ++j) p[i][j] = p1[i][j];
    }
    for (int i = 0; i < 6; ++i)
        for (int j = 0; j < 6; ++j) ws2[S_P + i * 6 + j] = p[i][j];
}

// ---------------------------------------------------------------------------
// K5: out[j,n,d] = sum_i P[i][j] * invnV[i] * (av_d*V0[i,n,d] + cv_d)
// ---------------------------------------------------------------------------
__global__ __launch_bounds__(256) void combine_out(
    const bf16_t* __restrict__ VB, const float* __restrict__ ws2,
    float* __restrict__ out)
{
    float w[36];
#pragma unroll
    for (int c = 0; c < 36; ++c)
        w[c] = ws2[S_P + c] * ws2[S_INVN + 12 + c / 6];
    const float* av = ws2 + S_COEFA + 1024;
    const float* cv = ws2 + S_COEFC + 1024;

    const long total = (long)NPTS * 64;
    for (long it = (long)blockIdx.x * 256 + threadIdx.x; it < total;
         it += (long)gridDim.x * 256) {
        const int n  = (int)(it >> 6);
        const int d8 = (int)(it & 63);
        float a8[8], c8[8];
#pragma unroll
        for (int e = 0; e < 8; ++e) { a8[e] = av[d8 * 8 + e]; c8[e] = cv[d8 * 8 + e]; }

        float o[6][8];
#pragma unroll
        for (int j = 0; j < 6; ++j)
#pragma unroll
            for (int e = 0; e < 8; ++e) o[j][e] = 0.f;

#pragma unroll
        for (int i = 0; i < 6; ++i) {
            bf16x8 xv = *(const bf16x8*)(VB + ((long)i * NPTS + n) * DIM + d8 * 8);
            float vn[8];
#pragma unroll
            for (int e = 0; e < 8; ++e) vn[e] = fmaf(a8[e], (float)xv[e], c8[e]);
#pragma unroll
            for (int j = 0; j < 6; ++j) {
                const float wi = w[i * 6 + j];
#pragma unroll
                for (int e = 0; e < 8; ++e) o[j][e] = fmaf(wi, vn[e], o[j][e]);
            }
        }
#pragma unroll
        for (int j = 0; j < 6; ++j) {
            float* dst = out + ((long)j * NPTS + n) * DIM + d8 * 8;
            *(float4*)dst       = *(const float4*)&o[j][0];
            *(float4*)(dst + 4) = *(const float4*)&o[j][4];
        }
    }
}

// ---------------------------------------------------------------------------
extern "C" void kernel_launch(void* const* d_in, const int* in_sizes, int n_in,
                              void* d_out, int out_size, void* d_ws, size_t ws_size,
                              hipStream_t stream)
{
    const float* X   = (const float*)d_in[0];
    const float* Wq  = (const float*)d_in[1];
    const float* bq  = (const float*)d_in[2];
    const float* Wk  = (const float*)d_in[3];
    const float* bk  = (const float*)d_in[4];
    const float* Wv  = (const float*)d_in[5];
    const float* bv  = (const float*)d_in[6];
    const float* gq  = (const float*)d_in[7];
    const float* beq = (const float*)d_in[8];
    const float* gk  = (const float*)d_in[9];
    const float* bek = (const float*)d_in[10];
    const float* gv  = (const float*)d_in[11];
    const float* bev = (const float*)d_in[12];

    char* w = (char*)d_ws;
    bf16_t* XB = (bf16_t*)(w + OFF_XB);
    bf16_t* QB = (bf16_t*)(w + OFF_QB);
    bf16_t* KB = (bf16_t*)(w + OFF_KB);
    bf16_t* VB = (bf16_t*)(w + OFF_VB);
    bf16_t* WB = (bf16_t*)(w + OFF_WB);
    float* ws2 = (float*)(w + OFF_F32);
    float* out = (float*)d_out;

    hipMemsetAsync(ws2, 0, S_END * sizeof(float), stream);

    convert_bf16<<<2048, 256, 0, stream>>>(X, XB, (long)M_TOTAL * DIM / 8);
    convert_bf16<<<128, 256, 0, stream>>>(Wq, WB,           (long)DIM * DIM / 8);
    convert_bf16<<<128, 256, 0, stream>>>(Wk, WB + 262144,  (long)DIM * DIM / 8);
    convert_bf16<<<128, 256, 0, stream>>>(Wv, WB + 524288,  (long)DIM * DIM / 8);

    gemm_qkv_mfma<<<15024, 256, 0, stream>>>(XB, WB, bq, bk, bv,
                                             ws2 + S_SUM, ws2 + S_SSQ, QB, KB, VB);
    finalize_stats<<<3, 512, 0, stream>>>(gq, beq, gk, bek, gv, bev, ws2);
    qk_dot<<<2048, 256, 0, stream>>>(QB, KB, ws2);
    project_kernel<<<1, 512, 0, stream>>>(ws2);
    combine_out<<<2048, 256, 0, stream>>>(VB, ws2, out);
}

// Round 9
// 1041.998 us; speedup vs baseline: 1.0685x; 1.0685x over previous
//
#include <hip/hip_runtime.h>

#define VIEWS 6
#define NPTS 20000
#define DIM 512
#define M_TOTAL (VIEWS * NPTS)

typedef __bf16 bf16_t;
typedef __attribute__((ext_vector_type(8))) __bf16 bf16x8;
typedef __attribute__((ext_vector_type(4))) float f32x4;

// ---- workspace byte offsets ----
#define OFF_XB 0L                      // X bf16  [6][20000][512]
#define OFF_QB 122880000L              // Q0 bf16
#define OFF_KB 245760000L              // K0 bf16
#define OFF_VB 368640000L              // V0 bf16
#define OFF_WB 491520000L              // W bf16  [3][512][512]
#define OFF_F32 493092864L             // fp32 stats region
// ---- float indices inside fp32 region ----
#define S_SUM 0                        // [3][6][512] per-channel sums
#define S_SSQ 9216                     // [3][6][512] per-channel sum-squares
#define S_PPRE 18432                   // [36] weighted gram accumulator
#define S_COEFA 18468                  // [3][512] BN scale a
#define S_COEFC 20004                  // [3][512] BN shift c
#define S_INVN 21540                   // [3][6] inverse Fro norms
#define S_P 21558                      // [36] final mixing matrix
#define S_END 21594

__device__ __forceinline__ void gload_lds16(const void* gsrc, void* lds) {
    __builtin_amdgcn_global_load_lds(
        (const __attribute__((address_space(1))) unsigned int*)gsrc,
        (__attribute__((address_space(3))) unsigned int*)lds,
        16, 0, 0);
}

// ---------------------------------------------------------------------------
// K0: fp32 -> bf16 convert of X and the three W matrices in ONE launch
// ---------------------------------------------------------------------------
__global__ __launch_bounds__(256) void convert_all(
    const float* __restrict__ X,
    const float* __restrict__ Wq, const float* __restrict__ Wk,
    const float* __restrict__ Wv,
    bf16_t* __restrict__ XB, bf16_t* __restrict__ WB)
{
    const long NX = (long)M_TOTAL * DIM / 8;   // 7,680,000 chunks of 8
    const long NW = (long)DIM * DIM / 8;       // 32,768 per W
    const long total = NX + 3 * NW;
    for (long i = (long)blockIdx.x * 256 + threadIdx.x; i < total;
         i += (long)gridDim.x * 256) {
        const float* s;
        bf16_t* d;
        if (i < NX) { s = X + i * 8; d = XB + i * 8; }
        else {
            long w = i - NX;
            int t = (int)(w / NW);
            long r = w - (long)t * NW;
            const float* W = (t == 0) ? Wq : (t == 1) ? Wk : Wv;
            s = W + r * 8;
            d = WB + w * 8;
        }
        float4 x = ((const float4*)s)[0], y = ((const float4*)s)[1];
        bf16x8 o;
        o[0] = (bf16_t)x.x; o[1] = (bf16_t)x.y; o[2] = (bf16_t)x.z; o[3] = (bf16_t)x.w;
        o[4] = (bf16_t)y.x; o[5] = (bf16_t)y.y; o[6] = (bf16_t)y.z; o[7] = (bf16_t)y.w;
        *(bf16x8*)d = o;
    }
}

// ---------------------------------------------------------------------------
// K1: bf16 MFMA GEMM  [Q0|K0|V0] = X @ W^T  (+bias, fp32 stats, bf16 store)
// Tile: 256 rows x 64 cols x ALL THREE tensors. 4 waves, each owns 64 rows.
// Per K-step: stage 56KB (A 32KB + 3xB 24KB), compute 384 MFMAs/block --
// 4x the MFMA-per-stage-event of the previous 64-row tile (the measured
// bottleneck: stage+vmcnt+barrier latency, not conflicts/fetch/BW).
// LDS XOR-swizzle kc^=(row&7) on stage-source and ds_read (0 conflicts, R7).
// Grid 3792 = 79 n-tiles x 8 c-tiles x 6 views, bijective XCD swizzle.
// ---------------------------------------------------------------------------
__global__ __launch_bounds__(256, 2) void gemm_qkv_mfma(
    const bf16_t* __restrict__ XB, const bf16_t* __restrict__ WB,
    const float* __restrict__ b0, const float* __restrict__ b1,
    const float* __restrict__ b2,
    float* __restrict__ statS, float* __restrict__ statQ,
    bf16_t* __restrict__ QB, bf16_t* __restrict__ KB, bf16_t* __restrict__ VB)
{
    // bijective XCD swizzle: nwg=3792=8*474
    const int orig = blockIdx.x;
    const int L    = (orig & 7) * 474 + (orig >> 3);
    const int n0i  = L / 48;
    const int rem  = L - n0i * 48;
    const int v    = rem >> 3;            // view
    const int c0   = (rem & 7) << 6;      // channel tile base (64 wide)
    const int n0   = n0i * 256;
    const int nvalid = min(256, NPTS - n0);

    const int tid  = threadIdx.x;
    const int wid  = tid >> 6;
    const int lane = tid & 63;
    const int lr   = lane & 15;
    const int lk   = lane >> 4;

    // LDS: As[256][64] bf16 (32KB) + Bs[3][64][64] (24KB) = 56KB
    __shared__ char smem[57344];

    const bf16_t* Ag = XB + ((long)v * NPTS + n0) * DIM;

    f32x4 acc[3][4][4];                   // [tensor][fm(row frag)][fn(col frag)]
    const f32x4 zero4 = {0.f, 0.f, 0.f, 0.f};
#pragma unroll
    for (int t = 0; t < 3; ++t)
#pragma unroll
        for (int i = 0; i < 4; ++i)
#pragma unroll
            for (int j = 0; j < 4; ++j) acc[t][i][j] = zero4;

    for (int k0 = 0; k0 < DIM; k0 += 64) {
        __syncthreads();
        // stage 3584 chunks of 16B: 2048 A + 3*512 B. 14 iters x 256 lanes.
        // source kc pre-swizzled (kc ^ row&7); LDS dest linear (rule 21).
#pragma unroll
        for (int i = 0; i < 14; ++i) {
            const int base = i * 256 + wid * 64;      // wave-uniform
            const int g    = base + lane;
            const bf16_t* src;
            if (g < 2048) {                           // A chunk
                const int row = g >> 3;               // 0..255
                const int kcs = (g & 7) ^ (row & 7);
                const int rowc = (row < nvalid) ? row : (nvalid - 1);
                src = Ag + (long)rowc * DIM + k0 + kcs * 8;
            } else {                                  // B chunk
                const int h   = g - 2048;             // 0..1535
                const int t   = h >> 9;
                const int idx = h & 511;
                const int row = idx >> 3;             // 0..63
                const int kcs = (idx & 7) ^ (row & 7);
                src = WB + ((long)t << 18) + (long)(c0 + row) * DIM + k0 + kcs * 8;
            }
            gload_lds16(src, smem + (long)base * 16);
        }
        __syncthreads();
#pragma unroll
        for (int ks = 0; ks < 2; ++ks) {
            const int kc = ks * 4 + lk;
            bf16x8 af[4];
#pragma unroll
            for (int fm = 0; fm < 4; ++fm) {
                const int rowA = wid * 64 + fm * 16 + lr;
                af[fm] = *(const bf16x8*)(smem + rowA * 128 + ((kc ^ (rowA & 7)) << 4));
            }
#pragma unroll
            for (int t = 0; t < 3; ++t) {
#pragma unroll
                for (int fn = 0; fn < 4; ++fn) {
                    const int rowB = fn * 16 + lr;
                    bf16x8 bf = *(const bf16x8*)(smem + 32768 + t * 8192 +
                                                 rowB * 128 + ((kc ^ (rowB & 7)) << 4));
#pragma unroll
                    for (int fm = 0; fm < 4; ++fm)
                        acc[t][fm][fn] = __builtin_amdgcn_mfma_f32_16x16x32_bf16(
                            af[fm], bf, acc[t][fm][fn], 0, 0, 0);
                }
            }
        }
    }

    // epilogue: per tensor: bias, bf16 store, per-channel stats
    __syncthreads();
    float* redS = (float*)smem;           // alias dead As region
    float* redQ = redS + 64;
    for (int t = 0; t < 3; ++t) {
        if (tid < 128) redS[tid] = 0.f;   // zeroes redS[64]+redQ[64]
        __syncthreads();
        bf16_t* Obuf = (t == 0) ? QB : (t == 1) ? KB : VB;
        const float* bias = (t == 0) ? b0 : (t == 1) ? b1 : b2;
#pragma unroll
        for (int fn = 0; fn < 4; ++fn) {
            const int cl  = fn * 16 + lr;
            const int col = c0 + cl;
            const float bv_ = bias[col];
            float cs = 0.f, cq = 0.f;
#pragma unroll
            for (int fm = 0; fm < 4; ++fm) {
#pragma unroll
                for (int r = 0; r < 4; ++r) {
                    const int row = wid * 64 + fm * 16 + lk * 4 + r;
                    if (row < nvalid) {
                        float val = acc[t][fm][fn][r] + bv_;
                        cs += val;
                        cq += val * val;
                        Obuf[((long)v * NPTS + n0 + row) * DIM + col] = (bf16_t)val;
                    }
                }
            }
            atomicAdd(&redS[cl], cs);
            atomicAdd(&redQ[cl], cq);
        }
        __syncthreads();
        if (tid < 64) {
            atomicAdd(&statS[(((long)t * 6 + v) << 9) + c0 + tid], redS[tid]);
            atomicAdd(&statQ[(((long)t * 6 + v) << 9) + c0 + tid], redQ[tid]);
        }
        __syncthreads();
    }
}

// ---------------------------------------------------------------------------
// K2: BN affine coefficients + per-view inverse Frobenius norms
// ---------------------------------------------------------------------------
__global__ __launch_bounds__(512) void finalize_stats(
    const float* __restrict__ gq, const float* __restrict__ beq,
    const float* __restrict__ gk, const float* __restrict__ bek,
    const float* __restrict__ gv, const float* __restrict__ bev,
    float* __restrict__ ws2)
{
    const int t = blockIdx.x;
    const int c = threadIdx.x;
    const float* g  = (t == 0) ? gq : (t == 1) ? gk : gv;
    const float* be = (t == 0) ? beq : (t == 1) ? bek : bev;
    const float* sumbuf = ws2 + S_SUM + (long)t * 6 * 512;
    const float* ssqbuf = ws2 + S_SSQ + (long)t * 6 * 512;

    float s[6], q[6];
    float tot = 0.f, totq = 0.f;
#pragma unroll
    for (int v = 0; v < 6; ++v) {
        s[v] = sumbuf[v * 512 + c];
        q[v] = ssqbuf[v * 512 + c];
        tot += s[v]; totq += q[v];
    }
    const float invM = 1.0f / (float)M_TOTAL;
    float mean = tot * invM;
    float var  = totq * invM - mean * mean;
    float a    = g[c] * rsqrtf(var + 1e-5f);
    float cc   = be[c] - a * mean;
    ws2[S_COEFA + t * 512 + c] = a;
    ws2[S_COEFC + t * 512 + c] = cc;

    __shared__ float red[512];
    for (int v = 0; v < 6; ++v) {
        red[c] = a * a * q[v] + 2.f * a * cc * s[v] + (float)NPTS * cc * cc;
        __syncthreads();
        for (int off = 256; off > 0; off >>= 1) {
            if (c < off) red[c] += red[c + off];
            __syncthreads();
        }
        if (c == 0) ws2[S_INVN + t * 6 + v] = 1.f / (sqrtf(red[0]) + 1e-8f);
        __syncthreads();
    }
}

// ---------------------------------------------------------------------------
// K3: weighted gram  PPRE[i][j] += sum_{n,c} (aq_c*ak_c) Q0[i,n,c] K0[j,n,c]
// ---------------------------------------------------------------------------
__global__ __launch_bounds__(256) void qk_dot(
    const bf16_t* __restrict__ QB, const bf16_t* __restrict__ KB,
    float* __restrict__ ws2)
{
    float acc[36];
#pragma unroll
    for (int c = 0; c < 36; ++c) acc[c] = 0.f;

    const float* cA = ws2 + S_COEFA;
    const long total = (long)NPTS * 64;
    for (long it = (long)blockIdx.x * 256 + threadIdx.x; it < total;
         it += (long)gridDim.x * 256) {
        const int n  = (int)(it >> 6);
        const int d8 = (int)(it & 63);

        float w8[8];
#pragma unroll
        for (int e = 0; e < 8; ++e)
            w8[e] = cA[d8 * 8 + e] * cA[512 + d8 * 8 + e];

        float qw[6][8];
#pragma unroll
        for (int i = 0; i < 6; ++i) {
            bf16x8 qv = *(const bf16x8*)(QB + ((long)i * NPTS + n) * DIM + d8 * 8);
#pragma unroll
            for (int e = 0; e < 8; ++e) qw[i][e] = (float)qv[e] * w8[e];
        }
#pragma unroll
        for (int j = 0; j < 6; ++j) {
            bf16x8 kv = *(const bf16x8*)(KB + ((long)j * NPTS + n) * DIM + d8 * 8);
            float kf[8];
#pragma unroll
            for (int e = 0; e < 8; ++e) kf[e] = (float)kv[e];
#pragma unroll
            for (int i = 0; i < 6; ++i) {
                float d = 0.f;
#pragma unroll
                for (int e = 0; e < 8; ++e) d = fmaf(qw[i][e], kf[e], d);
                acc[i * 6 + j] += d;
            }
        }
    }

    __shared__ float part[36];
    if (threadIdx.x < 36) part[threadIdx.x] = 0.f;
    __syncthreads();
    const int lane = threadIdx.x & 63;
#pragma unroll
    for (int c = 0; c < 36; ++c) {
        float x = acc[c];
#pragma unroll
        for (int m = 1; m < 64; m <<= 1) x += __shfl_xor(x, m);
        if (lane == 0) atomicAdd(&part[c], x);
    }
    __syncthreads();
    if (threadIdx.x < 36) atomicAdd(&ws2[S_PPRE + threadIdx.x], part[threadIdx.x]);
}

// ---------------------------------------------------------------------------
// K4: cross terms + sigmoid + softmax mix + 10-step projection
// ---------------------------------------------------------------------------
__global__ __launch_bounds__(512) void project_kernel(float* __restrict__ ws2)
{
    const int c = threadIdx.x;   // 0..511
    __shared__ float red[512];
    const float aq = ws2[S_COEFA + c],       cq = ws2[S_COEFC + c];
    const float ak = ws2[S_COEFA + 512 + c], ck = ws2[S_COEFC + 512 + c];

    float vals[13];
#pragma unroll
    for (int i = 0; i < 6; ++i) vals[i]     = aq * ck * ws2[S_SUM + i * 512 + c];
#pragma unroll
    for (int j = 0; j < 6; ++j) vals[6 + j] = cq * ak * ws2[S_SUM + (6 + j) * 512 + c];
    vals[12] = cq * ck;

    float out13[13];
#pragma unroll
    for (int r = 0; r < 13; ++r) {
        red[c] = vals[r];
        __syncthreads();
        for (int off = 256; off > 0; off >>= 1) {
            if (c < off) red[c] += red[c + off];
            __syncthreads();
        }
        out13[r] = red[0];
        __syncthreads();
    }

    if (c != 0) return;

    const float* invn = ws2 + S_INVN;
    float p[6][6];
    for (int i = 0; i < 6; ++i)
        for (int j = 0; j < 6; ++j) {
            float raw = ws2[S_PPRE + i * 6 + j] + out13[i] + out13[6 + j] +
                        (float)NPTS * out13[12];
            float z = raw * invn[i] * invn[6 + j];
            p[i][j] = 1.f / (1.f + expf(-z));
        }
    float s0[6][6], s1[6][6];
    for (int j = 0; j < 6; ++j) {
        float m = -1e30f;
        for (int i = 0; i < 6; ++i) m = fmaxf(m, p[i][j]);
        float sum = 0.f;
        for (int i = 0; i < 6; ++i) { s0[i][j] = expf(p[i][j] - m); sum += s0[i][j]; }
        for (int i = 0; i < 6; ++i) s0[i][j] /= sum;
    }
    for (int i = 0; i < 6; ++i) {
        float m = -1e30f;
        for (int j = 0; j < 6; ++j) m = fmaxf(m, p[i][j]);
        float sum = 0.f;
        for (int j = 0; j < 6; ++j) { s1[i][j] = expf(p[i][j] - m); sum += s1[i][j]; }
        for (int j = 0; j < 6; ++j) s1[i][j] /= sum;
    }
    for (int i = 0; i < 6; ++i)
        for (int j = 0; j < 6; ++j) p[i][j] = 0.5f * (s0[i][j] + s1[i][j]);

    for (int itr = 0; itr < 10; ++itr) {
        float p1[6][6];
        for (int i = 0; i < 6; ++i)
            for (int j = 0; j < 6; ++j) p1[i][j] = fmaxf(p[i][j], 0.f);
        for (int i = 0; i < 6; ++i) {
            float rs = 0.f;
            for (int j = 0; j < 6; ++j) rs += p1[i][j];
            float adj = (rs - 1.f) * (1.f / 6.f);
            for (int j = 0; j < 6; ++j) p1[i][j] -= adj;
        }
        for (int j = 0; j < 6; ++j) {
            float cs = 0.f;
            for (int i = 0; i < 6; ++i) cs += p1[i][j];
            float adj = (cs - 1.f) * (1.f / 6.f);
            for (int i = 0; i < 6; ++i) p1[i][j] -= adj;
        }
        for (int i = 0; i < 6; ++i)
            for (int j = 0; j < 6; ++j) p[i][j] = p1[i][j];
    }
    for (int i = 0; i < 6; ++i)
        for (int j = 0; j < 6; ++j) ws2[S_P + i * 6 + j] = p[i][j];
}

// ---------------------------------------------------------------------------
// K5: out[j,n,d] = sum_i P[i][j] * invnV[i] * (av_d*V0[i,n,d] + cv_d)
// ---------------------------------------------------------------------------
__global__ __launch_bounds__(256) void combine_out(
    const bf16_t* __restrict__ VB, const float* __restrict__ ws2,
    float* __restrict__ out)
{
    float w[36];
#pragma unroll
    for (int c = 0; c < 36; ++c)
        w[c] = ws2[S_P + c] * ws2[S_INVN + 12 + c / 6];
    const float* av = ws2 + S_COEFA + 1024;
    const float* cv = ws2 + S_COEFC + 1024;

    const long total = (long)NPTS * 64;
    for (long it = (long)blockIdx.x * 256 + threadIdx.x; it < total;
         it += (long)gridDim.x * 256) {
        const int n  = (int)(it >> 6);
        const int d8 = (int)(it & 63);
        float a8[8], c8[8];
#pragma unroll
        for (int e = 0; e < 8; ++e) { a8[e] = av[d8 * 8 + e]; c8[e] = cv[d8 * 8 + e]; }

        float o[6][8];
#pragma unroll
        for (int j = 0; j < 6; ++j)
#pragma unroll
            for (int e = 0; e < 8; ++e) o[j][e] = 0.f;

#pragma unroll
        for (int i = 0; i < 6; ++i) {
            bf16x8 xv = *(const bf16x8*)(VB + ((long)i * NPTS + n) * DIM + d8 * 8);
            float vn[8];
#pragma unroll
            for (int e = 0; e < 8; ++e) vn[e] = fmaf(a8[e], (float)xv[e], c8[e]);
#pragma unroll
            for (int j = 0; j < 6; ++j) {
                const float wi = w[i * 6 + j];
#pragma unroll
                for (int e = 0; e < 8; ++e) o[j][e] = fmaf(wi, vn[e], o[j][e]);
            }
        }
#pragma unroll
        for (int j = 0; j < 6; ++j) {
            float* dst = out + ((long)j * NPTS + n) * DIM + d8 * 8;
            *(float4*)dst       = *(const float4*)&o[j][0];
            *(float4*)(dst + 4) = *(const float4*)&o[j][4];
        }
    }
}

// ---------------------------------------------------------------------------
extern "C" void kernel_launch(void* const* d_in, const int* in_sizes, int n_in,
                              void* d_out, int out_size, void* d_ws, size_t ws_size,
                              hipStream_t stream)
{
    const float* X   = (const float*)d_in[0];
    const float* Wq  = (const float*)d_in[1];
    const float* bq  = (const float*)d_in[2];
    const float* Wk  = (const float*)d_in[3];
    const float* bk  = (const float*)d_in[4];
    const float* Wv  = (const float*)d_in[5];
    const float* bv  = (const float*)d_in[6];
    const float* gq  = (const float*)d_in[7];
    const float* beq = (const float*)d_in[8];
    const float* gk  = (const float*)d_in[9];
    const float* bek = (const float*)d_in[10];
    const float* gv  = (const float*)d_in[11];
    const float* bev = (const float*)d_in[12];

    char* w = (char*)d_ws;
    bf16_t* XB = (bf16_t*)(w + OFF_XB);
    bf16_t* QB = (bf16_t*)(w + OFF_QB);
    bf16_t* KB = (bf16_t*)(w + OFF_KB);
    bf16_t* VB = (bf16_t*)(w + OFF_VB);
    bf16_t* WB = (bf16_t*)(w + OFF_WB);
    float* ws2 = (float*)(w + OFF_F32);
    float* out = (float*)d_out;

    hipMemsetAsync(ws2, 0, S_END * sizeof(float), stream);

    convert_all<<<2048, 256, 0, stream>>>(X, Wq, Wk, Wv, XB, WB);

    gemm_qkv_mfma<<<3792, 256, 0, stream>>>(XB, WB, bq, bk, bv,
                                            ws2 + S_SUM, ws2 + S_SSQ, QB, KB, VB);
    finalize_stats<<<3, 512, 0, stream>>>(gq, beq, gk, bek, gv, bev, ws2);
    qk_dot<<<2048, 256, 0, stream>>>(QB, KB, ws2);
    project_kernel<<<1, 512, 0, stream>>>(ws2);
    combine_out<<<2048, 256, 0, stream>>>(VB, ws2, out);
}